// Round 14
// baseline (220.700 us; speedup 1.0000x reference)
//
#include <hip/hip_runtime.h>
#include <hip/hip_bf16.h>

#define IN_FEAT 256
#define HEADS 4
#define OUT_FEAT 64
#define NEG_SLOPE 0.2f

typedef __bf16 bf16x8 __attribute__((ext_vector_type(8)));
typedef float f32x4 __attribute__((ext_vector_type(4)));

__device__ inline unsigned short f2bf(float f) {
    union { float f; unsigned u; } v; v.f = f;
    unsigned r = v.u + 0x7FFF + ((v.u >> 16) & 1);   // RNE, finite inputs
    return (unsigned short)(r >> 16);
}
__device__ inline float bf2f(unsigned short u) {
    union { unsigned u; float f; } v; v.u = ((unsigned)u) << 16; return v.f;
}

// ---------------- merged: X/W bf16 pre-swizzled convert + dst histogram -----
__global__ __launch_bounds__(256) void hist_cvt(const int* __restrict__ ei,
                                                int* __restrict__ counts,
                                                const float* __restrict__ X,
                                                const float* __restrict__ W,
                                                unsigned short* __restrict__ Xb,
                                                unsigned short* __restrict__ Wtb,
                                                int E, int N, int nCvt) {
    const int tid = threadIdx.x;
    if ((int)blockIdx.x >= nCvt) {
        int idx = (blockIdx.x - nCvt) * 256 + tid;
        int stride = (gridDim.x - nCvt) * 256;
        for (int e = idx; e < E; e += stride) {
            int d = ei[E + e];
            if ((unsigned)d < (unsigned)N) atomicAdd(&counts[d], 1);
        }
        return;
    }
    // chunk c (16B) of K-group g in row r stored at c ^ (r&7)
    const int totalX = N * 32;
    const int total = totalX + 256 * 32;
    int idx = blockIdx.x * 256 + tid;
    if (idx >= total) return;
    if (idx < totalX) {
        int r = idx >> 5, j = idx & 31;
        int g = j >> 3, c = j & 7;
        const float4 v0 = *reinterpret_cast<const float4*>(&X[(size_t)r * 256 + j * 8]);
        const float4 v1 = *reinterpret_cast<const float4*>(&X[(size_t)r * 256 + j * 8 + 4]);
        ushort4 p0, p1;
        p0.x = f2bf(v0.x); p0.y = f2bf(v0.y); p0.z = f2bf(v0.z); p0.w = f2bf(v0.w);
        p1.x = f2bf(v1.x); p1.y = f2bf(v1.y); p1.z = f2bf(v1.z); p1.w = f2bf(v1.w);
        unsigned short* dst = &Xb[(size_t)r * 256 + (g * 8 + (c ^ (r & 7))) * 8];
        *reinterpret_cast<ushort4*>(dst) = p0;
        *reinterpret_cast<ushort4*>(dst + 4) = p1;
    } else {
        int t = idx - totalX;
        int n = t >> 5, j = t & 31;
        int g = j >> 3, c = j & 7;
        ushort4 p0, p1;
        p0.x = f2bf(W[(size_t)(j * 8 + 0) * 256 + n]);
        p0.y = f2bf(W[(size_t)(j * 8 + 1) * 256 + n]);
        p0.z = f2bf(W[(size_t)(j * 8 + 2) * 256 + n]);
        p0.w = f2bf(W[(size_t)(j * 8 + 3) * 256 + n]);
        p1.x = f2bf(W[(size_t)(j * 8 + 4) * 256 + n]);
        p1.y = f2bf(W[(size_t)(j * 8 + 5) * 256 + n]);
        p1.z = f2bf(W[(size_t)(j * 8 + 6) * 256 + n]);
        p1.w = f2bf(W[(size_t)(j * 8 + 7) * 256 + n]);
        unsigned short* dst = &Wtb[(size_t)n * 256 + (g * 8 + (c ^ (n & 7))) * 8];
        *reinterpret_cast<ushort4*>(dst) = p0;
        *reinterpret_cast<ushort4*>(dst + 4) = p1;
    }
}

// Parallel scan: per-1024 tile local scan + one atomicAdd to reserve the base.
__global__ __launch_bounds__(1024) void scan_atomic(const int* __restrict__ counts,
                                                    int* __restrict__ offsets,
                                                    int* __restrict__ cursor,
                                                    int* __restrict__ gcur, int N) {
    __shared__ int sdata[1024];
    __shared__ int sbase;
    const int t = threadIdx.x;
    const int i = blockIdx.x * 1024 + t;
    const int v = (i < N) ? counts[i] : 0;
    sdata[t] = v;
    __syncthreads();
    for (int off = 1; off < 1024; off <<= 1) {
        int u = (t >= off) ? sdata[t - off] : 0;
        __syncthreads();
        sdata[t] += u;
        __syncthreads();
    }
    if (t == 1023) sbase = atomicAdd(gcur, sdata[1023]);
    __syncthreads();
    if (i < N) {
        int excl = sbase + sdata[t] - v;
        offsets[i] = excl;
        cursor[i] = excl;
    }
}

// ---------------- XCD-partitioned scatter -----------------------------------
__global__ __launch_bounds__(256) void scatter_kernel(const int* __restrict__ ei,
                                                      int* __restrict__ cursor,
                                                      int* __restrict__ sorted_src,
                                                      int E, int N) {
    const int part = blockIdx.x & 7;
    const int rsize = (N + 7) >> 3;
    const int lo = part * rsize;
    const int hi = min(lo + rsize, N);
    int lid = (blockIdx.x >> 3) * 256 + threadIdx.x;
    int lstride = (gridDim.x >> 3) * 256;
    for (int e = lid; e < E; e += lstride) {
        int d = ei[E + e];
        if (d < lo || d >= hi) continue;
        int s = ei[e];
        if ((unsigned)s >= (unsigned)N) continue;
        int pos = atomicAdd(&cursor[d], 1);
        sorted_src[pos] = s;
    }
}

// ---------------- Hb = bf16(Xb @ Wtb^T), fused per-head logits --------------
// 128x128 tile, BK=64, 4 waves (each 32 rows x 128 cols), single-buffered
// 32 KB LDS (-> ~3 blocks/CU), reg prefetch distance 1. m97-shaped loop.
__global__ __launch_bounds__(256) void gemm_mfma(const unsigned short* __restrict__ Xb,
                                                 const unsigned short* __restrict__ Wtb,
                                                 const float* __restrict__ att_src,
                                                 const float* __restrict__ att_dst,
                                                 unsigned short* __restrict__ Hb,
                                                 float* __restrict__ asrc,
                                                 float* __restrict__ adst, int M) {
    __shared__ __align__(16) unsigned short sMem[16384];  // 32 KB: sA 16K | sB 16K
    const int bx = blockIdx.x;
    const int bm = (bx >> 1) * 128;
    const int bn = (bx & 1) * 128;
    const int h0 = bn >> 6;           // 0 or 2
    const int tid = threadIdx.x;
    const int lane = tid & 63;
    const int wid = tid >> 6;         // 0..3: 32-row slice
    const uint4* Xb4 = reinterpret_cast<const uint4*>(Xb);
    const uint4* Wtb4 = reinterpret_cast<const uint4*>(Wtb);
    unsigned short* sA = sMem;
    unsigned short* sB = sMem + 8192;
    uint4* dA = reinterpret_cast<uint4*>(sA);
    uint4* dB = reinterpret_cast<uint4*>(sB);

    f32x4 acc[2][8] = {};
    uint4 pa[4], pb[4], qa[4], qb[4];

#define LOADS(a, b, g)                                                            \
    {                                                                             \
        _Pragma("unroll")                                                         \
        for (int i = 0; i < 4; ++i) {                                             \
            int ci = i * 256 + tid;                                               \
            a[i] = Xb4[(size_t)(bm + (ci >> 3)) * 32 + (g) * 8 + (ci & 7)];       \
        }                                                                         \
        _Pragma("unroll")                                                         \
        for (int j = 0; j < 4; ++j) {                                             \
            int ci = j * 256 + tid;                                               \
            b[j] = Wtb4[(size_t)(bn + (ci >> 3)) * 32 + (g) * 8 + (ci & 7)];      \
        }                                                                         \
    }

#define WRITE(a, b)                                                               \
    {                                                                             \
        _Pragma("unroll")                                                         \
        for (int i = 0; i < 4; ++i) dA[i * 256 + tid] = a[i];                     \
        _Pragma("unroll")                                                         \
        for (int j = 0; j < 4; ++j) dB[j * 256 + tid] = b[j];                     \
    }

#define COMPUTE()                                                                 \
    {                                                                             \
        __builtin_amdgcn_s_setprio(1);                                            \
        _Pragma("unroll")                                                         \
        for (int kk = 0; kk < 2; ++kk) {                                          \
            bf16x8 af[2], bfr[8];                                                 \
            const int c = kk * 4 + (lane >> 4);                                   \
            _Pragma("unroll")                                                     \
            for (int m = 0; m < 2; ++m) {                                         \
                int r = wid * 32 + m * 16 + (lane & 15);                          \
                af[m] = *reinterpret_cast<const bf16x8*>(                         \
                    &sA[r * 64 + ((c ^ (r & 7)) << 3)]);                          \
            }                                                                     \
            _Pragma("unroll")                                                     \
            for (int nf = 0; nf < 8; ++nf) {                                      \
                int n = nf * 16 + (lane & 15);                                    \
                bfr[nf] = *reinterpret_cast<const bf16x8*>(                       \
                    &sB[n * 64 + ((c ^ (n & 7)) << 3)]);                          \
            }                                                                     \
            _Pragma("unroll")                                                     \
            for (int m = 0; m < 2; ++m)                                           \
                _Pragma("unroll")                                                 \
                for (int nf = 0; nf < 8; ++nf)                                    \
                    acc[m][nf] = __builtin_amdgcn_mfma_f32_16x16x32_bf16(         \
                        af[m], bfr[nf], acc[m][nf], 0, 0, 0);                     \
        }                                                                         \
        __builtin_amdgcn_s_setprio(0);                                            \
    }

    LOADS(pa, pb, 0);
    // g=0
    WRITE(pa, pb);
    LOADS(qa, qb, 1);
    __syncthreads();
    COMPUTE();
    __syncthreads();
    // g=1
    WRITE(qa, qb);
    LOADS(pa, pb, 2);
    __syncthreads();
    COMPUTE();
    __syncthreads();
    // g=2
    WRITE(pa, pb);
    LOADS(qa, qb, 3);
    __syncthreads();
    COMPUTE();
    __syncthreads();
    // g=3
    WRITE(qa, qb);
    __syncthreads();
    COMPUTE();
#undef LOADS
#undef WRITE
#undef COMPUTE

    // ---- fused logits from fragments ----
    float attS[8], attD[8];
#pragma unroll
    for (int nf = 0; nf < 8; ++nf) {
        int col = bn + nf * 16 + (lane & 15);
        attS[nf] = att_src[col];
        attD[nf] = att_dst[col];
    }
    __syncthreads();   // all LDS reads done; sC may overwrite sA/sB
    unsigned short* sC = sMem;    // 128 x 128 bf16 = 32 KB
#pragma unroll
    for (int m = 0; m < 2; ++m)
#pragma unroll
        for (int i = 0; i < 4; ++i) {
            int rl = wid * 32 + m * 16 + ((lane >> 4) << 2) + i;   // local row
            int R = bm + rl;
            float p0s = 0.f, p0d = 0.f, p1s = 0.f, p1d = 0.f;
            const int swz = (rl >> 2) & 7;
#pragma unroll
            for (int nf = 0; nf < 8; ++nf) {
                float v = acc[m][nf][i];
                if (nf < 4) { p0s += v * attS[nf]; p0d += v * attD[nf]; }
                else        { p1s += v * attS[nf]; p1d += v * attD[nf]; }
                sC[rl * 128 + ((nf ^ swz) << 4) + (lane & 15)] = f2bf(v);
            }
#pragma unroll
            for (int off = 1; off < 16; off <<= 1) {
                p0s += __shfl_xor(p0s, off, 64);
                p0d += __shfl_xor(p0d, off, 64);
                p1s += __shfl_xor(p1s, off, 64);
                p1d += __shfl_xor(p1d, off, 64);
            }
            if ((lane & 15) == 0 && R < M) {
                asrc[R * HEADS + h0]     = p0s;
                asrc[R * HEADS + h0 + 1] = p1s;
                adst[R * HEADS + h0]     = p0d;
                adst[R * HEADS + h0 + 1] = p1d;
            }
        }
    __syncthreads();
    // ---- coalesced store: 256B row segments (4 full 64B lines each) ----
#pragma unroll
    for (int it = 0; it < 8; ++it) {
        int gc = it * 256 + tid;          // 16B chunk id, 16 per row
        int r = gc >> 4;
        int j = gc & 15;
        int cs = (j >> 1) ^ ((r >> 2) & 7);
        const uint4 v = *reinterpret_cast<const uint4*>(
            &sC[r * 128 + (cs << 4) + (j & 1) * 8]);
        if (bm + r < M)
            *reinterpret_cast<uint4*>(&Hb[(size_t)(bm + r) * 256 + bn + j * 8]) = v;
    }
}

// ---------------- gather aggregate: one wave per dst, 2 edges in flight -----
__global__ __launch_bounds__(256) void aggregate(const unsigned short* __restrict__ Hb,
                                                 const float* __restrict__ asrc,
                                                 const float* __restrict__ adst,
                                                 const int* __restrict__ offsets,
                                                 const int* __restrict__ counts,
                                                 const int* __restrict__ sorted_src,
                                                 const float* __restrict__ bias,
                                                 float* __restrict__ out, int N) {
    int gtid = blockIdx.x * blockDim.x + threadIdx.x;
    int wave = gtid >> 6;
    int lane = threadIdx.x & 63;
    int nwaves = (gridDim.x * blockDim.x) >> 6;
    const int half = lane >> 5;      // 0/1: which edge of the pair
    const int l32 = lane & 31;       // feature slot: [l32*8, l32*8+8)
    const int head = l32 >> 3;
    float bv[8];
#pragma unroll
    for (int i = 0; i < 8; ++i) bv[i] = bias[l32 * 8 + i];

    for (int d = wave; d < N; d += nwaves) {
        const float ad = adst[d * HEADS + head];
        float accv[8];
        float den;
        {   // self-loop handled by half 0 only
            float a = asrc[d * HEADS + head] + ad;
            float w = (half == 0) ? __expf((a > 0.f) ? a : NEG_SLOPE * a) : 0.f;
            const ushort4 h0 = *reinterpret_cast<const ushort4*>(&Hb[(size_t)d * 256 + l32 * 8]);
            const ushort4 h1 = *reinterpret_cast<const ushort4*>(&Hb[(size_t)d * 256 + l32 * 8 + 4]);
            accv[0] = w * bf2f(h0.x); accv[1] = w * bf2f(h0.y);
            accv[2] = w * bf2f(h0.z); accv[3] = w * bf2f(h0.w);
            accv[4] = w * bf2f(h1.x); accv[5] = w * bf2f(h1.y);
            accv[6] = w * bf2f(h1.z); accv[7] = w * bf2f(h1.w);
            den = w;
        }
        const int start = offsets[d];
        const int cnt = counts[d];
        int k = half;
        for (; k + 2 < cnt; k += 4) {
            int sA_ = sorted_src[start + k];
            int sB_ = sorted_src[start + k + 2];
            float aA = asrc[sA_ * HEADS + head] + ad;
            float aB = asrc[sB_ * HEADS + head] + ad;
            const ushort4 a0 = *reinterpret_cast<const ushort4*>(&Hb[(size_t)sA_ * 256 + l32 * 8]);
            const ushort4 a1 = *reinterpret_cast<const ushort4*>(&Hb[(size_t)sA_ * 256 + l32 * 8 + 4]);
            const ushort4 b0 = *reinterpret_cast<const ushort4*>(&Hb[(size_t)sB_ * 256 + l32 * 8]);
            const ushort4 b1 = *reinterpret_cast<const ushort4*>(&Hb[(size_t)sB_ * 256 + l32 * 8 + 4]);
            float wA = __expf((aA > 0.f) ? aA : NEG_SLOPE * aA);
            float wB = __expf((aB > 0.f) ? aB : NEG_SLOPE * aB);
            accv[0] += wA * bf2f(a0.x) + wB * bf2f(b0.x);
            accv[1] += wA * bf2f(a0.y) + wB * bf2f(b0.y);
            accv[2] += wA * bf2f(a0.z) + wB * bf2f(b0.z);
            accv[3] += wA * bf2f(a0.w) + wB * bf2f(b0.w);
            accv[4] += wA * bf2f(a1.x) + wB * bf2f(b1.x);
            accv[5] += wA * bf2f(a1.y) + wB * bf2f(b1.y);
            accv[6] += wA * bf2f(a1.z) + wB * bf2f(b1.z);
            accv[7] += wA * bf2f(a1.w) + wB * bf2f(b1.w);
            den += wA + wB;
        }
        for (; k < cnt; k += 2) {
            int s0 = sorted_src[start + k];
            float a0f = asrc[s0 * HEADS + head] + ad;
            const ushort4 u0 = *reinterpret_cast<const ushort4*>(&Hb[(size_t)s0 * 256 + l32 * 8]);
            const ushort4 u1 = *reinterpret_cast<const ushort4*>(&Hb[(size_t)s0 * 256 + l32 * 8 + 4]);
            float w0 = __expf((a0f > 0.f) ? a0f : NEG_SLOPE * a0f);
            accv[0] += w0 * bf2f(u0.x); accv[1] += w0 * bf2f(u0.y);
            accv[2] += w0 * bf2f(u0.z); accv[3] += w0 * bf2f(u0.w);
            accv[4] += w0 * bf2f(u1.x); accv[5] += w0 * bf2f(u1.y);
            accv[6] += w0 * bf2f(u1.z); accv[7] += w0 * bf2f(u1.w);
            den += w0;
        }
#pragma unroll
        for (int i = 0; i < 8; ++i) accv[i] += __shfl_xor(accv[i], 32, 64);
        den += __shfl_xor(den, 32, 64);
        if (half == 0) {
            const float inv = 1.f / den;
            float4 r0, r1;
            r0.x = fmaxf(accv[0] * inv + bv[0], 0.f);
            r0.y = fmaxf(accv[1] * inv + bv[1], 0.f);
            r0.z = fmaxf(accv[2] * inv + bv[2], 0.f);
            r0.w = fmaxf(accv[3] * inv + bv[3], 0.f);
            r1.x = fmaxf(accv[4] * inv + bv[4], 0.f);
            r1.y = fmaxf(accv[5] * inv + bv[5], 0.f);
            r1.z = fmaxf(accv[6] * inv + bv[6], 0.f);
            r1.w = fmaxf(accv[7] * inv + bv[7], 0.f);
            *reinterpret_cast<float4*>(&out[(size_t)d * 256 + l32 * 8]) = r0;
            *reinterpret_cast<float4*>(&out[(size_t)d * 256 + l32 * 8 + 4]) = r1;
        }
    }
}

extern "C" void kernel_launch(void* const* d_in, const int* in_sizes, int n_in,
                              void* d_out, int out_size, void* d_ws, size_t ws_size,
                              hipStream_t stream) {
    const float* x       = (const float*)d_in[0];
    const int*   ei      = (const int*)d_in[1];      // harness converts int64 -> int32
    const float* W       = (const float*)d_in[2];
    const float* att_src = (const float*)d_in[3];
    const float* att_dst = (const float*)d_in[4];
    const float* bias    = (const float*)d_in[5];
    float*       out     = (float*)d_out;

    const int N = in_sizes[0] / IN_FEAT;   // 50000
    const int E = in_sizes[1] / 2;         // 800000
    const int Npad = (N + 127) & ~127;     // 50048

    // workspace layout
    unsigned short* Xb = (unsigned short*)d_ws;               // Npad*256 bf16
    unsigned short* Hb = Xb + (size_t)Npad * IN_FEAT;         // Npad*256 bf16
    float* asrc       = (float*)(Hb + (size_t)Npad * IN_FEAT);
    float* adst       = asrc + (size_t)N * HEADS;
    int*   counts     = (int*)(adst + (size_t)N * HEADS);
    int*   offsets    = counts + N;
    int*   cursor     = offsets + N;
    int*   sorted_src = cursor + N;                           // E
    int*   gcur       = sorted_src + E;                       // 4 ints (align)
    unsigned short* Wtb = (unsigned short*)(gcur + 4);        // 256*256 bf16

    hipMemsetAsync(counts, 0, (size_t)N * sizeof(int), stream);
    hipMemsetAsync(gcur, 0, 4 * sizeof(int), stream);

    // X/W bf16 pre-convert || dst histogram — one kernel, both LDS-free
    {
        int nCvt = (N * 32 + 256 * 32 + 255) / 256;
        hist_cvt<<<nCvt + 1024, 256, 0, stream>>>(ei, counts, x, W, Xb, Wtb, E, N, nCvt);
    }
    scan_atomic<<<(N + 1023) / 1024, 1024, 0, stream>>>(counts, offsets, cursor, gcur, N);

    // XCD-partitioned scatter: full-line writebacks instead of per-store RMW
    scatter_kernel<<<2048, 256, 0, stream>>>(ei, cursor, sorted_src, E, N);

    gemm_mfma<<<(Npad / 128) * 2, 256, 0, stream>>>(Xb, Wtb, att_src, att_dst,
                                                    Hb, asrc, adst, N);

    aggregate<<<(N * 64 + 255) / 256, 256, 0, stream>>>(Hb, asrc, adst, offsets, counts,
                                                        sorted_src, bias, out, N);
}

// Round 15
// 205.071 us; speedup vs baseline: 1.0762x; 1.0762x over previous
//
#include <hip/hip_runtime.h>
#include <hip/hip_bf16.h>

#define IN_FEAT 256
#define HEADS 4
#define OUT_FEAT 64
#define NEG_SLOPE 0.2f

typedef __bf16 bf16x8 __attribute__((ext_vector_type(8)));
typedef float f32x4 __attribute__((ext_vector_type(4)));

__device__ inline unsigned short f2bf(float f) {
    union { float f; unsigned u; } v; v.f = f;
    unsigned r = v.u + 0x7FFF + ((v.u >> 16) & 1);   // RNE, finite inputs
    return (unsigned short)(r >> 16);
}
__device__ inline float bf2f(unsigned short u) {
    union { unsigned u; float f; } v; v.u = ((unsigned)u) << 16; return v.f;
}

// ---------------- merged: X/W bf16 pre-swizzled convert + dst histogram -----
__global__ __launch_bounds__(256) void hist_cvt(const int* __restrict__ ei,
                                                int* __restrict__ counts,
                                                const float* __restrict__ X,
                                                const float* __restrict__ W,
                                                unsigned short* __restrict__ Xb,
                                                unsigned short* __restrict__ Wtb,
                                                int E, int N, int nCvt) {
    const int tid = threadIdx.x;
    if ((int)blockIdx.x >= nCvt) {
        int idx = (blockIdx.x - nCvt) * 256 + tid;
        int stride = (gridDim.x - nCvt) * 256;
        for (int e = idx; e < E; e += stride) {
            int d = ei[E + e];
            if ((unsigned)d < (unsigned)N) atomicAdd(&counts[d], 1);
        }
        return;
    }
    // chunk c (16B) of K-group g in row r stored at c ^ (r&7)
    const int totalX = N * 32;
    const int total = totalX + 256 * 32;
    int idx = blockIdx.x * 256 + tid;
    if (idx >= total) return;
    if (idx < totalX) {
        int r = idx >> 5, j = idx & 31;
        int g = j >> 3, c = j & 7;
        const float4 v0 = *reinterpret_cast<const float4*>(&X[(size_t)r * 256 + j * 8]);
        const float4 v1 = *reinterpret_cast<const float4*>(&X[(size_t)r * 256 + j * 8 + 4]);
        ushort4 p0, p1;
        p0.x = f2bf(v0.x); p0.y = f2bf(v0.y); p0.z = f2bf(v0.z); p0.w = f2bf(v0.w);
        p1.x = f2bf(v1.x); p1.y = f2bf(v1.y); p1.z = f2bf(v1.z); p1.w = f2bf(v1.w);
        unsigned short* dst = &Xb[(size_t)r * 256 + (g * 8 + (c ^ (r & 7))) * 8];
        *reinterpret_cast<ushort4*>(dst) = p0;
        *reinterpret_cast<ushort4*>(dst + 4) = p1;
    } else {
        int t = idx - totalX;
        int n = t >> 5, j = t & 31;
        int g = j >> 3, c = j & 7;
        ushort4 p0, p1;
        p0.x = f2bf(W[(size_t)(j * 8 + 0) * 256 + n]);
        p0.y = f2bf(W[(size_t)(j * 8 + 1) * 256 + n]);
        p0.z = f2bf(W[(size_t)(j * 8 + 2) * 256 + n]);
        p0.w = f2bf(W[(size_t)(j * 8 + 3) * 256 + n]);
        p1.x = f2bf(W[(size_t)(j * 8 + 4) * 256 + n]);
        p1.y = f2bf(W[(size_t)(j * 8 + 5) * 256 + n]);
        p1.z = f2bf(W[(size_t)(j * 8 + 6) * 256 + n]);
        p1.w = f2bf(W[(size_t)(j * 8 + 7) * 256 + n]);
        unsigned short* dst = &Wtb[(size_t)n * 256 + (g * 8 + (c ^ (n & 7))) * 8];
        *reinterpret_cast<ushort4*>(dst) = p0;
        *reinterpret_cast<ushort4*>(dst + 4) = p1;
    }
}

// Parallel scan: per-1024 tile local scan + one atomicAdd to reserve the base.
__global__ __launch_bounds__(1024) void scan_atomic(const int* __restrict__ counts,
                                                    int* __restrict__ offsets,
                                                    int* __restrict__ cursor,
                                                    int* __restrict__ gcur, int N) {
    __shared__ int sdata[1024];
    __shared__ int sbase;
    const int t = threadIdx.x;
    const int i = blockIdx.x * 1024 + t;
    const int v = (i < N) ? counts[i] : 0;
    sdata[t] = v;
    __syncthreads();
    for (int off = 1; off < 1024; off <<= 1) {
        int u = (t >= off) ? sdata[t - off] : 0;
        __syncthreads();
        sdata[t] += u;
        __syncthreads();
    }
    if (t == 1023) sbase = atomicAdd(gcur, sdata[1023]);
    __syncthreads();
    if (i < N) {
        int excl = sbase + sdata[t] - v;
        offsets[i] = excl;
        cursor[i] = excl;
    }
}

// ---------------- Hb = bf16(Xb @ Wtb^T) — pure GEMM, Hb-only epilogue -------
// 128x256 tile, BK=64, 8 waves 4(m)x2(n), LDS dbuf, prefetch distance 2.
__global__ __launch_bounds__(512) void gemm_mfma(const unsigned short* __restrict__ Xb,
                                                 const unsigned short* __restrict__ Wtb,
                                                 unsigned short* __restrict__ Hb, int M) {
    __shared__ __align__(16) unsigned short sMem[2 * 24576];  // 96 KB
    const int brow = blockIdx.x * 128;
    const int tid = threadIdx.x;
    const int lane = tid & 63;
    const int wid = tid >> 6;
    const int wr = wid >> 1;          // 0..3 (32-row slice)
    const int wc = wid & 1;           // 0..1 (128-col half)
    const uint4* Xb4 = reinterpret_cast<const uint4*>(Xb);
    const uint4* Wtb4 = reinterpret_cast<const uint4*>(Wtb);

    f32x4 acc[2][8] = {};
    uint4 pa0[2], pb0[4], pa1[2], pb1[4];

#define LOADS(pa, pb, g)                                                          \
    {                                                                             \
        _Pragma("unroll")                                                         \
        for (int i = 0; i < 2; ++i) {                                             \
            int ci = i * 512 + tid;                                               \
            pa[i] = Xb4[(size_t)(brow + (ci >> 3)) * 32 + (g) * 8 + (ci & 7)];    \
        }                                                                         \
        _Pragma("unroll")                                                         \
        for (int j = 0; j < 4; ++j) {                                             \
            int ci = j * 512 + tid;                                               \
            pb[j] = Wtb4[(size_t)(ci >> 3) * 32 + (g) * 8 + (ci & 7)];            \
        }                                                                         \
    }

#define WRITE(par, pa, pb)                                                        \
    {                                                                             \
        uint4* dA = reinterpret_cast<uint4*>(sMem + (par) * 24576);               \
        uint4* dB = dA + 1024;                                                    \
        dA[tid] = pa[0];                                                          \
        dA[tid + 512] = pa[1];                                                    \
        _Pragma("unroll")                                                         \
        for (int j = 0; j < 4; ++j) dB[tid + j * 512] = pb[j];                    \
    }

#define COMPUTE(par)                                                              \
    {                                                                             \
        const unsigned short* sA = sMem + (par) * 24576;                          \
        const unsigned short* sB = sA + 8192;                                     \
        __builtin_amdgcn_s_setprio(1);                                            \
        _Pragma("unroll")                                                         \
        for (int kk = 0; kk < 2; ++kk) {                                          \
            bf16x8 af[2], bfr[8];                                                 \
            const int c = kk * 4 + (lane >> 4);                                   \
            _Pragma("unroll")                                                     \
            for (int m = 0; m < 2; ++m) {                                         \
                int r = wr * 32 + m * 16 + (lane & 15);                           \
                af[m] = *reinterpret_cast<const bf16x8*>(                         \
                    &sA[r * 64 + ((c ^ (r & 7)) << 3)]);                          \
            }                                                                     \
            _Pragma("unroll")                                                     \
            for (int nf = 0; nf < 8; ++nf) {                                      \
                int n = wc * 128 + nf * 16 + (lane & 15);                         \
                bfr[nf] = *reinterpret_cast<const bf16x8*>(                       \
                    &sB[n * 64 + ((c ^ (n & 7)) << 3)]);                          \
            }                                                                     \
            _Pragma("unroll")                                                     \
            for (int m = 0; m < 2; ++m)                                           \
                _Pragma("unroll")                                                 \
                for (int nf = 0; nf < 8; ++nf)                                    \
                    acc[m][nf] = __builtin_amdgcn_mfma_f32_16x16x32_bf16(         \
                        af[m], bfr[nf], acc[m][nf], 0, 0, 0);                     \
        }                                                                         \
        __builtin_amdgcn_s_setprio(0);                                            \
    }

    LOADS(pa0, pb0, 0);
    LOADS(pa1, pb1, 1);
    WRITE(0, pa0, pb0);
    LOADS(pa0, pb0, 2);
    __syncthreads();
    COMPUTE(0);
    __syncthreads();
    WRITE(1, pa1, pb1);
    LOADS(pa1, pb1, 3);
    __syncthreads();
    COMPUTE(1);
    __syncthreads();
    WRITE(0, pa0, pb0);
    __syncthreads();
    COMPUTE(0);
    __syncthreads();
    WRITE(1, pa1, pb1);
    __syncthreads();
    COMPUTE(1);
#undef LOADS
#undef WRITE
#undef COMPUTE

    __syncthreads();   // all LDS reads done; sC may overwrite buffers
    unsigned short* sC = sMem;    // 128 x 256 bf16 = 64 KB
#pragma unroll
    for (int m = 0; m < 2; ++m)
#pragma unroll
        for (int i = 0; i < 4; ++i) {
            int rl = wr * 32 + m * 16 + ((lane >> 4) << 2) + i;   // local row
            const int swz = (rl >> 2) & 3;
#pragma unroll
            for (int nf = 0; nf < 8; ++nf) {
                int chunk = wc * 8 + nf;              // 32B chunks, swizzled
                sC[rl * 256 + ((chunk ^ swz) << 4) + (lane & 15)] = f2bf(acc[m][nf][i]);
            }
        }
    __syncthreads();
    // ---- coalesced store: full 512B rows ----
#pragma unroll
    for (int it = 0; it < 8; ++it) {
        int gc = it * 512 + tid;          // 16B chunk id, 32 per row
        int r = gc >> 5;
        int j = gc & 31;
        int cs = (j >> 1) ^ ((r >> 2) & 3);
        const uint4 v = *reinterpret_cast<const uint4*>(
            &sC[r * 256 + (cs << 4) + (j & 1) * 8]);
        if (brow + r < M)
            *reinterpret_cast<uint4*>(&Hb[(size_t)(brow + r) * 256 + j * 8]) = v;
    }
}

// ---------------- merged: per-node logits (from bf16 Hb) + edge scatter -----
// blocks [0, NL): logits; [NL, grid): XCD-partitioned scatter. Independent.
__global__ __launch_bounds__(256) void scatter_logits(const unsigned short* __restrict__ Hb,
                                                      const float* __restrict__ att_src,
                                                      const float* __restrict__ att_dst,
                                                      float* __restrict__ asrc,
                                                      float* __restrict__ adst,
                                                      const int* __restrict__ ei,
                                                      int* __restrict__ cursor,
                                                      int* __restrict__ sorted_src,
                                                      int E, int N, int NL) {
    const int tid = threadIdx.x;
    if ((int)blockIdx.x >= NL) {
        // ---- XCD-partitioned scatter (NL is a multiple of 8) ----
        int sb = blockIdx.x - NL;
        const int part = sb & 7;
        const int rsize = (N + 7) >> 3;
        const int lo = part * rsize;
        const int hi = min(lo + rsize, N);
        int lid = (sb >> 3) * 256 + tid;
        int lstride = (((int)gridDim.x - NL) >> 3) * 256;
        for (int e = lid; e < E; e += lstride) {
            int d = ei[E + e];
            if (d < lo || d >= hi) continue;
            int s = ei[e];
            if ((unsigned)s >= (unsigned)N) continue;
            int pos = atomicAdd(&cursor[d], 1);
            sorted_src[pos] = s;
        }
        return;
    }
    // ---- logits: one wave per node; lane covers 4 features (8B load) ----
    int wave = blockIdx.x * 4 + (tid >> 6);
    int lane = tid & 63;
    int nwaves = NL * 4;
    const float4 as = *reinterpret_cast<const float4*>(&att_src[lane * 4]);
    const float4 ad = *reinterpret_cast<const float4*>(&att_dst[lane * 4]);
    for (int i = wave; i < N; i += nwaves) {
        const ushort4 hu = *reinterpret_cast<const ushort4*>(&Hb[(size_t)i * 256 + lane * 4]);
        float h0 = bf2f(hu.x), h1 = bf2f(hu.y), h2 = bf2f(hu.z), h3 = bf2f(hu.w);
        float ps = h0 * as.x + h1 * as.y + h2 * as.z + h3 * as.w;
        float pd = h0 * ad.x + h1 * ad.y + h2 * ad.z + h3 * ad.w;
#pragma unroll
        for (int off = 1; off < 16; off <<= 1) {
            ps += __shfl_xor(ps, off, 64);
            pd += __shfl_xor(pd, off, 64);
        }
        if ((lane & 15) == 0) {
            int head = lane >> 4;
            asrc[i * HEADS + head] = ps;
            adst[i * HEADS + head] = pd;
        }
    }
}

// ---------------- gather aggregate: one wave per dst, 2 edges in flight -----
__global__ __launch_bounds__(256) void aggregate(const unsigned short* __restrict__ Hb,
                                                 const float* __restrict__ asrc,
                                                 const float* __restrict__ adst,
                                                 const int* __restrict__ offsets,
                                                 const int* __restrict__ counts,
                                                 const int* __restrict__ sorted_src,
                                                 const float* __restrict__ bias,
                                                 float* __restrict__ out, int N) {
    int gtid = blockIdx.x * blockDim.x + threadIdx.x;
    int wave = gtid >> 6;
    int lane = threadIdx.x & 63;
    int nwaves = (gridDim.x * blockDim.x) >> 6;
    const int half = lane >> 5;      // 0/1: which edge of the pair
    const int l32 = lane & 31;       // feature slot: [l32*8, l32*8+8)
    const int head = l32 >> 3;
    float bv[8];
#pragma unroll
    for (int i = 0; i < 8; ++i) bv[i] = bias[l32 * 8 + i];

    for (int d = wave; d < N; d += nwaves) {
        const float ad = adst[d * HEADS + head];
        float accv[8];
        float den;
        {   // self-loop handled by half 0 only
            float a = asrc[d * HEADS + head] + ad;
            float w = (half == 0) ? __expf((a > 0.f) ? a : NEG_SLOPE * a) : 0.f;
            const ushort4 h0 = *reinterpret_cast<const ushort4*>(&Hb[(size_t)d * 256 + l32 * 8]);
            const ushort4 h1 = *reinterpret_cast<const ushort4*>(&Hb[(size_t)d * 256 + l32 * 8 + 4]);
            accv[0] = w * bf2f(h0.x); accv[1] = w * bf2f(h0.y);
            accv[2] = w * bf2f(h0.z); accv[3] = w * bf2f(h0.w);
            accv[4] = w * bf2f(h1.x); accv[5] = w * bf2f(h1.y);
            accv[6] = w * bf2f(h1.z); accv[7] = w * bf2f(h1.w);
            den = w;
        }
        const int start = offsets[d];
        const int cnt = counts[d];
        int k = half;
        for (; k + 2 < cnt; k += 4) {
            int sA_ = sorted_src[start + k];
            int sB_ = sorted_src[start + k + 2];
            float aA = asrc[sA_ * HEADS + head] + ad;
            float aB = asrc[sB_ * HEADS + head] + ad;
            const ushort4 a0 = *reinterpret_cast<const ushort4*>(&Hb[(size_t)sA_ * 256 + l32 * 8]);
            const ushort4 a1 = *reinterpret_cast<const ushort4*>(&Hb[(size_t)sA_ * 256 + l32 * 8 + 4]);
            const ushort4 b0 = *reinterpret_cast<const ushort4*>(&Hb[(size_t)sB_ * 256 + l32 * 8]);
            const ushort4 b1 = *reinterpret_cast<const ushort4*>(&Hb[(size_t)sB_ * 256 + l32 * 8 + 4]);
            float wA = __expf((aA > 0.f) ? aA : NEG_SLOPE * aA);
            float wB = __expf((aB > 0.f) ? aB : NEG_SLOPE * aB);
            accv[0] += wA * bf2f(a0.x) + wB * bf2f(b0.x);
            accv[1] += wA * bf2f(a0.y) + wB * bf2f(b0.y);
            accv[2] += wA * bf2f(a0.z) + wB * bf2f(b0.z);
            accv[3] += wA * bf2f(a0.w) + wB * bf2f(b0.w);
            accv[4] += wA * bf2f(a1.x) + wB * bf2f(b1.x);
            accv[5] += wA * bf2f(a1.y) + wB * bf2f(b1.y);
            accv[6] += wA * bf2f(a1.z) + wB * bf2f(b1.z);
            accv[7] += wA * bf2f(a1.w) + wB * bf2f(b1.w);
            den += wA + wB;
        }
        for (; k < cnt; k += 2) {
            int s0 = sorted_src[start + k];
            float a0f = asrc[s0 * HEADS + head] + ad;
            const ushort4 u0 = *reinterpret_cast<const ushort4*>(&Hb[(size_t)s0 * 256 + l32 * 8]);
            const ushort4 u1 = *reinterpret_cast<const ushort4*>(&Hb[(size_t)s0 * 256 + l32 * 8 + 4]);
            float w0 = __expf((a0f > 0.f) ? a0f : NEG_SLOPE * a0f);
            accv[0] += w0 * bf2f(u0.x); accv[1] += w0 * bf2f(u0.y);
            accv[2] += w0 * bf2f(u0.z); accv[3] += w0 * bf2f(u0.w);
            accv[4] += w0 * bf2f(u1.x); accv[5] += w0 * bf2f(u1.y);
            accv[6] += w0 * bf2f(u1.z); accv[7] += w0 * bf2f(u1.w);
            den += w0;
        }
#pragma unroll
        for (int i = 0; i < 8; ++i) accv[i] += __shfl_xor(accv[i], 32, 64);
        den += __shfl_xor(den, 32, 64);
        if (half == 0) {
            const float inv = 1.f / den;
            float4 r0, r1;
            r0.x = fmaxf(accv[0] * inv + bv[0], 0.f);
            r0.y = fmaxf(accv[1] * inv + bv[1], 0.f);
            r0.z = fmaxf(accv[2] * inv + bv[2], 0.f);
            r0.w = fmaxf(accv[3] * inv + bv[3], 0.f);
            r1.x = fmaxf(accv[4] * inv + bv[4], 0.f);
            r1.y = fmaxf(accv[5] * inv + bv[5], 0.f);
            r1.z = fmaxf(accv[6] * inv + bv[6], 0.f);
            r1.w = fmaxf(accv[7] * inv + bv[7], 0.f);
            *reinterpret_cast<float4*>(&out[(size_t)d * 256 + l32 * 8]) = r0;
            *reinterpret_cast<float4*>(&out[(size_t)d * 256 + l32 * 8 + 4]) = r1;
        }
    }
}

extern "C" void kernel_launch(void* const* d_in, const int* in_sizes, int n_in,
                              void* d_out, int out_size, void* d_ws, size_t ws_size,
                              hipStream_t stream) {
    const float* x       = (const float*)d_in[0];
    const int*   ei      = (const int*)d_in[1];      // harness converts int64 -> int32
    const float* W       = (const float*)d_in[2];
    const float* att_src = (const float*)d_in[3];
    const float* att_dst = (const float*)d_in[4];
    const float* bias    = (const float*)d_in[5];
    float*       out     = (float*)d_out;

    const int N = in_sizes[0] / IN_FEAT;   // 50000
    const int E = in_sizes[1] / 2;         // 800000
    const int Npad = (N + 127) & ~127;     // 50048

    // workspace layout
    unsigned short* Xb = (unsigned short*)d_ws;               // Npad*256 bf16
    unsigned short* Hb = Xb + (size_t)Npad * IN_FEAT;         // Npad*256 bf16
    float* asrc       = (float*)(Hb + (size_t)Npad * IN_FEAT);
    float* adst       = asrc + (size_t)N * HEADS;
    int*   counts     = (int*)(adst + (size_t)N * HEADS);
    int*   offsets    = counts + N;
    int*   cursor     = offsets + N;
    int*   sorted_src = cursor + N;                           // E
    int*   gcur       = sorted_src + E;                       // 4 ints (align)
    unsigned short* Wtb = (unsigned short*)(gcur + 4);        // 256*256 bf16

    hipMemsetAsync(counts, 0, (size_t)N * sizeof(int), stream);
    hipMemsetAsync(gcur, 0, 4 * sizeof(int), stream);

    // X/W bf16 pre-convert || dst histogram
    {
        int nCvt = (N * 32 + 256 * 32 + 255) / 256;
        hist_cvt<<<nCvt + 1024, 256, 0, stream>>>(ei, counts, x, W, Xb, Wtb, E, N, nCvt);
    }
    scan_atomic<<<(N + 1023) / 1024, 1024, 0, stream>>>(counts, offsets, cursor, gcur, N);

    // pure GEMM (Hb only)
    gemm_mfma<<<Npad / 128, 512, 0, stream>>>(Xb, Wtb, Hb, N);

    // node logits (from Hb) || XCD-partitioned edge scatter — independent
    {
        const int NL = 768;               // multiple of 8
        const int NS = 2048;
        scatter_logits<<<NL + NS, 256, 0, stream>>>(Hb, att_src, att_dst, asrc, adst,
                                                    ei, cursor, sorted_src, E, N, NL);
    }

    aggregate<<<(N * 64 + 255) / 256, 256, 0, stream>>>(Hb, asrc, adst, offsets, counts,
                                                        sorted_src, bias, out, N);
}